// Round 7
// baseline (588.820 us; speedup 1.0000x reference)
//
#include <hip/hip_runtime.h>
#include <hip/hip_bf16.h>

// GAT 2-layer. N=100000, L1: H=4,C=32 (HC=128), L2: H=1,C=32.
//
// R1: CSR gather instead of float-atomic scatter (1588 -> 826 us).
// R2: cooperative softmax via shfl broadcast (826 -> 734).
// R3: single-pass softmax, float4 loads, 8-deep unroll (734 -> 595).
// R4: atomic-free scatter; bf16 h payload; 16-deep unroll (595 -> 491).
// R5: both GEMMs -> bf16 MFMA 16x16x32, zero LDS/barriers (491 -> 443),
//     but gather1 VGPR 64->68 crossed the 8-wave occupancy cliff.
// R6: __launch_bounds__(256,8) pins gathers at VGPR<=64 (8 waves/SIMD);
//     cast_x fused into gemm1 (fp32 A read + in-reg RTNE pack).
// Self-loops are implicit: edge ids >= E map to (n,n).

typedef __bf16 bf16x8 __attribute__((ext_vector_type(8)));
typedef float f32x4 __attribute__((ext_vector_type(4)));

__device__ __forceinline__ float lrelu(float v) { return v >= 0.f ? v : 0.2f * v; }

__device__ __forceinline__ unsigned f2bf(float f) {   // RTNE f32->bf16 (finite inputs)
    unsigned u = __float_as_uint(f);
    return (u + 0x7FFFu + ((u >> 16) & 1u)) >> 16;
}

__device__ __forceinline__ bf16x8 as_bf16x8(uint4 u) {
    union { uint4 u; bf16x8 b; } c; c.u = u; return c.b;
}

__device__ __forceinline__ void bf16x8_fma(uint4 hv, float a, float* acc) {
    acc[0] = fmaf(a, __uint_as_float(hv.x << 16), acc[0]);
    acc[1] = fmaf(a, __uint_as_float(hv.x & 0xFFFF0000u), acc[1]);
    acc[2] = fmaf(a, __uint_as_float(hv.y << 16), acc[2]);
    acc[3] = fmaf(a, __uint_as_float(hv.y & 0xFFFF0000u), acc[3]);
    acc[4] = fmaf(a, __uint_as_float(hv.z << 16), acc[4]);
    acc[5] = fmaf(a, __uint_as_float(hv.z & 0xFFFF0000u), acc[5]);
    acc[6] = fmaf(a, __uint_as_float(hv.w << 16), acc[6]);
    acc[7] = fmaf(a, __uint_as_float(hv.w & 0xFFFF0000u), acc[7]);
}

// ---------------- weight cast: W1[128,128] -> w1t[c][k] bf16 ; W2 -> w2t[c][k]
__global__ __launch_bounds__(256) void cast_w_k(const float* __restrict__ W1,
                                                const float* __restrict__ W2,
                                                ushort* __restrict__ w1t,
                                                ushort* __restrict__ w2t) {
    int tid = blockIdx.x * 256 + threadIdx.x;
    if (tid < 16384) {
        int k = tid >> 7, c = tid & 127;
        w1t[c * 128 + k] = (ushort)f2bf(W1[tid]);
    }
    if (tid < 4096) {
        int k = tid >> 5, c = tid & 31;
        w2t[c * 128 + k] = (ushort)f2bf(W2[tid]);
    }
}

// ---------------- GEMM1 (MFMA): x[N,128]fp32 (cast in-reg) @ W1 -> h[N,128]bf16 + as/ad
// Block: 64 rows, 4 waves x 16 rows. 8 col-tiles, K=128 in 4 steps. No LDS.
__global__ __launch_bounds__(256) void gemm1_mfma(
    const float* __restrict__ x, const ushort* __restrict__ w1t,
    const float* __restrict__ atts, const float* __restrict__ attd,
    ushort* __restrict__ h, float* __restrict__ as_, float* __restrict__ ad_, int N) {
    const int w = threadIdx.x >> 6;
    const int l = threadIdx.x & 63;
    const int c15 = l & 15;
    const int quad = l >> 4;
    const int n_base = blockIdx.x * 64 + w * 16;
    const int n = n_base + c15;

    bf16x8 a[4];
    if (n < N) {
        const float4* xr = (const float4*)(x + (size_t)n * 128);
#pragma unroll
        for (int ks = 0; ks < 4; ks++) {
            float4 p0 = xr[ks * 8 + quad * 2];
            float4 p1 = xr[ks * 8 + quad * 2 + 1];
            uint4 u;
            u.x = f2bf(p0.x) | (f2bf(p0.y) << 16);
            u.y = f2bf(p0.z) | (f2bf(p0.w) << 16);
            u.z = f2bf(p1.x) | (f2bf(p1.y) << 16);
            u.w = f2bf(p1.z) | (f2bf(p1.w) << 16);
            a[ks] = as_bf16x8(u);
        }
    } else {
        uint4 z = make_uint4(0, 0, 0, 0);
#pragma unroll
        for (int ks = 0; ks < 4; ks++) a[ks] = as_bf16x8(z);
    }

    f32x4 acc[8];
#pragma unroll
    for (int ct = 0; ct < 8; ct++) acc[ct] = (f32x4){0.f, 0.f, 0.f, 0.f};

#pragma unroll
    for (int ct = 0; ct < 8; ct++) {
        const uint4* wr = (const uint4*)(w1t + (size_t)(ct * 16 + c15) * 128);
#pragma unroll
        for (int ks = 0; ks < 4; ks++) {
            bf16x8 bfrag = as_bf16x8(wr[ks * 4 + quad]);
            acc[ct] = __builtin_amdgcn_mfma_f32_16x16x32_bf16(a[ks], bfrag, acc[ct], 0, 0, 0);
        }
    }

    // h stores: lane holds col=ct*16+c15, rows n_base+quad*4+reg
#pragma unroll
    for (int ct = 0; ct < 8; ct++) {
        int col = ct * 16 + c15;
#pragma unroll
        for (int reg = 0; reg < 4; reg++) {
            int n_out = n_base + quad * 4 + reg;
            if (n_out < N) h[(size_t)n_out * 128 + col] = (ushort)f2bf(acc[ct][reg]);
        }
    }
    // attention logits per head (cols of head hh live in tiles 2hh, 2hh+1)
#pragma unroll
    for (int hh = 0; hh < 4; hh++) {
        float sA = atts[hh * 32 + c15], sB = atts[hh * 32 + 16 + c15];
        float dA = attd[hh * 32 + c15], dB = attd[hh * 32 + 16 + c15];
#pragma unroll
        for (int reg = 0; reg < 4; reg++) {
            float ps = acc[2 * hh][reg] * sA + acc[2 * hh + 1][reg] * sB;
            float pd = acc[2 * hh][reg] * dA + acc[2 * hh + 1][reg] * dB;
            ps += __shfl_xor(ps, 1); pd += __shfl_xor(pd, 1);
            ps += __shfl_xor(ps, 2); pd += __shfl_xor(pd, 2);
            ps += __shfl_xor(ps, 4); pd += __shfl_xor(pd, 4);
            ps += __shfl_xor(ps, 8); pd += __shfl_xor(pd, 8);
            int n_out = n_base + quad * 4 + reg;
            if (c15 == 0 && n_out < N) { as_[n_out * 4 + hh] = ps; ad_[n_out * 4 + hh] = pd; }
        }
    }
}

// ---------------- GEMM2 (MFMA): o1[N,128]bf16 @ W2 -> h2[N,32]bf16 + as/ad --
__global__ __launch_bounds__(256) void gemm2_mfma(
    const ushort* __restrict__ ob, const ushort* __restrict__ w2t,
    const float* __restrict__ atts, const float* __restrict__ attd,
    ushort* __restrict__ h, float* __restrict__ as_, float* __restrict__ ad_, int N) {
    const int w = threadIdx.x >> 6;
    const int l = threadIdx.x & 63;
    const int c15 = l & 15;
    const int quad = l >> 4;
    const int n_base = blockIdx.x * 64 + w * 16;
    const int n = n_base + c15;

    bf16x8 a[4];
    if (n < N) {
        const uint4* xr = (const uint4*)(ob + (size_t)n * 128);
#pragma unroll
        for (int ks = 0; ks < 4; ks++) a[ks] = as_bf16x8(xr[ks * 4 + quad]);
    } else {
        uint4 z = make_uint4(0, 0, 0, 0);
#pragma unroll
        for (int ks = 0; ks < 4; ks++) a[ks] = as_bf16x8(z);
    }

    f32x4 acc[2];
#pragma unroll
    for (int ct = 0; ct < 2; ct++) acc[ct] = (f32x4){0.f, 0.f, 0.f, 0.f};

#pragma unroll
    for (int ct = 0; ct < 2; ct++) {
        const uint4* wr = (const uint4*)(w2t + (size_t)(ct * 16 + c15) * 128);
#pragma unroll
        for (int ks = 0; ks < 4; ks++) {
            bf16x8 bfrag = as_bf16x8(wr[ks * 4 + quad]);
            acc[ct] = __builtin_amdgcn_mfma_f32_16x16x32_bf16(a[ks], bfrag, acc[ct], 0, 0, 0);
        }
    }

#pragma unroll
    for (int ct = 0; ct < 2; ct++) {
        int col = ct * 16 + c15;
#pragma unroll
        for (int reg = 0; reg < 4; reg++) {
            int n_out = n_base + quad * 4 + reg;
            if (n_out < N) h[(size_t)n_out * 32 + col] = (ushort)f2bf(acc[ct][reg]);
        }
    }
    float sA = atts[c15], sB = atts[16 + c15];
    float dA = attd[c15], dB = attd[16 + c15];
#pragma unroll
    for (int reg = 0; reg < 4; reg++) {
        float ps = acc[0][reg] * sA + acc[1][reg] * sB;
        float pd = acc[0][reg] * dA + acc[1][reg] * dB;
        ps += __shfl_xor(ps, 1); pd += __shfl_xor(pd, 1);
        ps += __shfl_xor(ps, 2); pd += __shfl_xor(pd, 2);
        ps += __shfl_xor(ps, 4); pd += __shfl_xor(pd, 4);
        ps += __shfl_xor(ps, 8); pd += __shfl_xor(pd, 8);
        int n_out = n_base + quad * 4 + reg;
        if (c15 == 0 && n_out < N) { as_[n_out] = ps; ad_[n_out] = pd; }
    }
}

// ---------------- CSR build: hist+rank -> scan -> atomic-free scatter -------
__global__ __launch_bounds__(256) void hist_rank_k(const int* __restrict__ ei, int E, int N,
                                                   int* __restrict__ deg, int* __restrict__ rank) {
    int e = blockIdx.x * 256 + threadIdx.x;
    if (e >= E + N) return;
    int d = (e < E) ? ei[E + e] : e - E;
    rank[e] = atomicAdd(&deg[d], 1);
}

__global__ __launch_bounds__(256) void scan1_k(const int* __restrict__ deg,
                                               int* __restrict__ tmp, int* __restrict__ partial, int N) {
    __shared__ int sh[256];
    int i = blockIdx.x * 256 + threadIdx.x;
    int v = (i < N) ? deg[i] : 0;
    sh[threadIdx.x] = v;
    __syncthreads();
#pragma unroll
    for (int off = 1; off < 256; off <<= 1) {
        int t = (threadIdx.x >= off) ? sh[threadIdx.x - off] : 0;
        __syncthreads();
        sh[threadIdx.x] += t;
        __syncthreads();
    }
    if (i < N) tmp[i] = sh[threadIdx.x];
    if (threadIdx.x == 255) partial[blockIdx.x] = sh[255];
}

__global__ __launch_bounds__(1024) void scan2_k(int* __restrict__ partial, int B) {
    __shared__ int sh[1024];
    int i = threadIdx.x;
    int v = (i < B) ? partial[i] : 0;
    sh[i] = v;
    __syncthreads();
#pragma unroll
    for (int off = 1; off < 1024; off <<= 1) {
        int t = (i >= off) ? sh[i - off] : 0;
        __syncthreads();
        sh[i] += t;
        __syncthreads();
    }
    if (i < B) partial[i] = sh[i] - v;   // exclusive
}

__global__ __launch_bounds__(256) void scan3_k(const int* __restrict__ tmp, const int* __restrict__ partial,
                                               int* __restrict__ rs, int N) {
    int i = blockIdx.x * 256 + threadIdx.x;
    if (i < N) rs[i + 1] = tmp[i] + partial[blockIdx.x];
    if (i == 0) rs[0] = 0;
}

__global__ __launch_bounds__(256) void scatter_k(const int* __restrict__ ei, const int* __restrict__ rank,
                                                 const int* __restrict__ rs, int E, int N,
                                                 int* __restrict__ csr) {
    int e = blockIdx.x * 256 + threadIdx.x;
    if (e >= E + N) return;
    int s, d;
    if (e < E) { s = ei[e]; d = ei[E + e]; } else { s = e - E; d = s; }
    csr[rs[d] + rank[e]] = s;      // fire-and-forget random store
}

// ---------------- layer-1 gather: 16 lanes/dst, 8 bf16 ch/lane (uint4 loads),
// 16-edge chunks fully unrolled. Output packed bf16 (feeds gemm2 MFMA).
// (256,8): pin VGPR<=64 to stay on the 8-wave/SIMD side of the occupancy cliff.
__global__ __launch_bounds__(256, 8) void gather1_k(
    const int* __restrict__ rs, const int* __restrict__ csr,
    const float* __restrict__ as_, const float* __restrict__ ad_,
    const uint4* __restrict__ h, const float* __restrict__ b,
    ushort* __restrict__ o, int N) {
    const int jj = threadIdx.x & 31;
    const int l16 = jj & 15;
    const int sub = jj & 16;             // 16-lane subgroup base in 32-window
    const int d = blockIdx.x * 16 + (threadIdx.x >> 5) * 2 + (jj >> 4);
    if (d >= N) return;
    const int hl = l16 >> 2;             // my head
    const int sl = l16 & 3;              // my slot base
    const int beg = rs[d], end = rs[d + 1];
    const float adv = ad_[d * 4 + hl];

    float acc[8];
#pragma unroll
    for (int i = 0; i < 8; i++) acc[i] = 0.f;
    float den = 0.f;

    int j0 = beg;
    for (; j0 + 16 <= end; j0 += 16) {
        int sv0 = csr[j0 + sl];
        int sv1 = csr[j0 + sl + 4];
        int sv2 = csr[j0 + sl + 8];
        int sv3 = csr[j0 + sl + 12];
        float ex0 = __expf(fminf(lrelu(as_[sv0 * 4 + hl] + adv), 80.f));
        float ex1 = __expf(fminf(lrelu(as_[sv1 * 4 + hl] + adv), 80.f));
        float ex2 = __expf(fminf(lrelu(as_[sv2 * 4 + hl] + adv), 80.f));
        float ex3 = __expf(fminf(lrelu(as_[sv3 * 4 + hl] + adv), 80.f));
        den += ex0 + ex1 + ex2 + ex3;
#pragma unroll
        for (int k = 0; k < 4; k++) {
            float exk = (k == 0) ? ex0 : (k == 1) ? ex1 : (k == 2) ? ex2 : ex3;
            int   svk = (k == 0) ? sv0 : (k == 1) ? sv1 : (k == 2) ? sv2 : sv3;
#pragma unroll
            for (int q = 0; q < 4; q++) {
                int src = sub + (l16 & 12) + q;
                float a = __shfl(exk, src, 32);
                int   s = __shfl(svk, src, 32);
                uint4 hv = h[(size_t)s * 16 + l16];
                bf16x8_fma(hv, a, acc);
            }
        }
    }
    int r = end - j0;
    if (r > 0) {
        float exs[4] = {0.f, 0.f, 0.f, 0.f};
        int   svs[4] = {0, 0, 0, 0};
#pragma unroll
        for (int k = 0; k < 4; k++) {
            int slot = sl + 4 * k;
            if (slot < r) {
                int s = csr[j0 + slot];
                svs[k] = s;
                exs[k] = __expf(fminf(lrelu(as_[s * 4 + hl] + adv), 80.f));
                den += exs[k];
            }
        }
        for (int e = 0; e < r; e++) {
            int k = e >> 2, q = e & 3;
            float exk = (k == 0) ? exs[0] : (k == 1) ? exs[1] : (k == 2) ? exs[2] : exs[3];
            int   svk = (k == 0) ? svs[0] : (k == 1) ? svs[1] : (k == 2) ? svs[2] : svs[3];
            int src = sub + (l16 & 12) + q;
            float a = __shfl(exk, src, 32);
            int   s = __shfl(svk, src, 32);
            uint4 hv = h[(size_t)s * 16 + l16];
            bf16x8_fma(hv, a, acc);
        }
    }
    den += __shfl_xor(den, 1, 32);
    den += __shfl_xor(den, 2, 32);
    const float rcp = 1.f / (den + 1e-16f);
    float4 b0 = *(const float4*)&b[l16 * 8];
    float4 b1 = *(const float4*)&b[l16 * 8 + 4];
    float v0 = fmaxf(acc[0] * rcp + b0.x, 0.f);
    float v1 = fmaxf(acc[1] * rcp + b0.y, 0.f);
    float v2 = fmaxf(acc[2] * rcp + b0.z, 0.f);
    float v3 = fmaxf(acc[3] * rcp + b0.w, 0.f);
    float v4 = fmaxf(acc[4] * rcp + b1.x, 0.f);
    float v5 = fmaxf(acc[5] * rcp + b1.y, 0.f);
    float v6 = fmaxf(acc[6] * rcp + b1.z, 0.f);
    float v7 = fmaxf(acc[7] * rcp + b1.w, 0.f);
    uint4 pk;
    pk.x = f2bf(v0) | (f2bf(v1) << 16);
    pk.y = f2bf(v2) | (f2bf(v3) << 16);
    pk.z = f2bf(v4) | (f2bf(v5) << 16);
    pk.w = f2bf(v6) | (f2bf(v7) << 16);
    ((uint4*)o)[(size_t)d * 16 + l16] = pk;
}

// ---------------- layer-2 gather: 4 lanes/dst, 8 bf16 ch/lane, 16-edge chunks.
__global__ __launch_bounds__(256, 8) void gather2_k(
    const int* __restrict__ rs, const int* __restrict__ csr,
    const float* __restrict__ as_, const float* __restrict__ ad_,
    const uint4* __restrict__ h, const float* __restrict__ b,
    float* __restrict__ o, int N) {
    const int jj = threadIdx.x & 31;
    const int l4 = jj & 3;
    const int sub = jj & 28;             // 4-lane subgroup base
    const int d = blockIdx.x * 64 + (threadIdx.x >> 5) * 8 + (jj >> 2);
    if (d >= N) return;
    const int beg = rs[d], end = rs[d + 1];
    const float adv = ad_[d];

    float acc[8];
#pragma unroll
    for (int i = 0; i < 8; i++) acc[i] = 0.f;
    float den = 0.f;

    int j0 = beg;
    for (; j0 + 16 <= end; j0 += 16) {
        int sv0 = csr[j0 + l4];
        int sv1 = csr[j0 + l4 + 4];
        int sv2 = csr[j0 + l4 + 8];
        int sv3 = csr[j0 + l4 + 12];
        float ex0 = __expf(fminf(lrelu(as_[sv0] + adv), 80.f));
        float ex1 = __expf(fminf(lrelu(as_[sv1] + adv), 80.f));
        float ex2 = __expf(fminf(lrelu(as_[sv2] + adv), 80.f));
        float ex3 = __expf(fminf(lrelu(as_[sv3] + adv), 80.f));
        den += ex0 + ex1 + ex2 + ex3;
#pragma unroll
        for (int k = 0; k < 4; k++) {
            float exk = (k == 0) ? ex0 : (k == 1) ? ex1 : (k == 2) ? ex2 : ex3;
            int   svk = (k == 0) ? sv0 : (k == 1) ? sv1 : (k == 2) ? sv2 : sv3;
#pragma unroll
            for (int q = 0; q < 4; q++) {
                int src = sub + q;
                float a = __shfl(exk, src, 32);
                int   s = __shfl(svk, src, 32);
                uint4 hv = h[(size_t)s * 4 + l4];
                bf16x8_fma(hv, a, acc);
            }
        }
    }
    int r = end - j0;
    if (r > 0) {
        float exs[4] = {0.f, 0.f, 0.f, 0.f};
        int   svs[4] = {0, 0, 0, 0};
#pragma unroll
        for (int k = 0; k < 4; k++) {
            int slot = l4 + 4 * k;
            if (slot < r) {
                int s = csr[j0 + slot];
                svs[k] = s;
                exs[k] = __expf(fminf(lrelu(as_[s] + adv), 80.f));
                den += exs[k];
            }
        }
        for (int e = 0; e < r; e++) {
            int k = e >> 2, q = e & 3;
            float exk = (k == 0) ? exs[0] : (k == 1) ? exs[1] : (k == 2) ? exs[2] : exs[3];
            int   svk = (k == 0) ? svs[0] : (k == 1) ? svs[1] : (k == 2) ? svs[2] : svs[3];
            int src = sub + q;
            float a = __shfl(exk, src, 32);
            int   s = __shfl(svk, src, 32);
            uint4 hv = h[(size_t)s * 4 + l4];
            bf16x8_fma(hv, a, acc);
        }
    }
    den += __shfl_xor(den, 1, 32);
    den += __shfl_xor(den, 2, 32);
    const float rcp = 1.f / (den + 1e-16f);
    float4 b0 = *(const float4*)&b[l4 * 8];
    float4 b1 = *(const float4*)&b[l4 * 8 + 4];
    float4 o0, o1v;
    o0.x  = acc[0] * rcp + b0.x;
    o0.y  = acc[1] * rcp + b0.y;
    o0.z  = acc[2] * rcp + b0.z;
    o0.w  = acc[3] * rcp + b0.w;
    o1v.x = acc[4] * rcp + b1.x;
    o1v.y = acc[5] * rcp + b1.y;
    o1v.z = acc[6] * rcp + b1.z;
    o1v.w = acc[7] * rcp + b1.w;
    *(float4*)&o[(size_t)d * 32 + l4 * 8]     = o0;
    *(float4*)&o[(size_t)d * 32 + l4 * 8 + 4] = o1v;
}

extern "C" void kernel_launch(void* const* d_in, const int* in_sizes, int n_in,
                              void* d_out, int out_size, void* d_ws, size_t ws_size,
                              hipStream_t stream) {
    const float* x    = (const float*)d_in[0];
    const int*   ei   = (const int*)d_in[1];
    const float* W1   = (const float*)d_in[2];
    const float* as1v = (const float*)d_in[3];
    const float* ad1v = (const float*)d_in[4];
    const float* b1   = (const float*)d_in[5];
    const float* W2   = (const float*)d_in[6];
    const float* as2v = (const float*)d_in[7];
    const float* ad2v = (const float*)d_in[8];
    const float* b2   = (const float*)d_in[9];
    float* out = (float*)d_out;

    const int N = in_sizes[0] / 128;
    const int E = in_sizes[1] / 2;
    const int EN = E + N;
    const int B = (N + 255) / 256;   // scan chunks (must be <= 1024)

    // workspace layout
    char* base = (char*)d_ws;
    size_t o = 0;
    auto alloc = [&](size_t bytes) { void* p = base + o; o += (bytes + 255) & ~(size_t)255; return p; };
    ushort* w1t  = (ushort*)alloc((size_t)128 * 128 * 2);
    ushort* w2t  = (ushort*)alloc((size_t)32 * 128 * 2);
    ushort* h1   = (ushort*)alloc((size_t)N * 128 * 2);
    ushort* h2   = (ushort*)alloc((size_t)N * 32 * 2);
    ushort* o1   = (ushort*)alloc((size_t)N * 128 * 2);
    float*  as1  = (float*)alloc((size_t)N * 4 * 4);
    float*  ad1  = (float*)alloc((size_t)N * 4 * 4);
    float*  as2  = (float*)alloc((size_t)N * 4);
    float*  ad2  = (float*)alloc((size_t)N * 4);
    int*    deg  = (int*)alloc((size_t)N * 4);
    int*    tmp  = (int*)alloc((size_t)N * 4);
    int*    part = (int*)alloc((size_t)1024 * 4);
    int*    rs   = (int*)alloc((size_t)(N + 1) * 4);
    int*    rank = (int*)alloc((size_t)EN * 4);
    int*    csr  = (int*)alloc((size_t)EN * 4);

    hipMemsetAsync(deg, 0, (size_t)N * 4, stream);

    const int nbE = (EN + 255) / 256;
    const int nbN = (N + 255) / 256;
    const int nbG = (N + 63) / 64;

    // ---- weight cast + layer-1 GEMM (MFMA, fused x cast) + CSR build
    cast_w_k<<<64, 256, 0, stream>>>(W1, W2, w1t, w2t);
    gemm1_mfma<<<nbG, 256, 0, stream>>>(x, w1t, as1v, ad1v, h1, as1, ad1, N);
    hist_rank_k<<<nbE, 256, 0, stream>>>(ei, E, N, deg, rank);
    scan1_k<<<nbN, 256, 0, stream>>>(deg, tmp, part, N);
    scan2_k<<<1, 1024, 0, stream>>>(part, B);
    scan3_k<<<nbN, 256, 0, stream>>>(tmp, part, rs, N);
    scatter_k<<<nbE, 256, 0, stream>>>(ei, rank, rs, E, N, csr);

    // ---- layer 1 edge softmax + aggregate + bias + relu -> o1 (bf16)
    gather1_k<<<(N + 15) / 16, 256, 0, stream>>>(rs, csr, as1, ad1, (const uint4*)h1, b1, o1, N);

    // ---- layer 2
    gemm2_mfma<<<nbG, 256, 0, stream>>>(o1, w2t, as2v, ad2v, h2, as2, ad2, N);
    gather2_k<<<(N + 63) / 64, 256, 0, stream>>>(rs, csr, as2, ad2, (const uint4*)h2, b2, out, N);
}

// Round 8
// 412.649 us; speedup vs baseline: 1.4269x; 1.4269x over previous
//
#include <hip/hip_runtime.h>
#include <hip/hip_bf16.h>

// GAT 2-layer. N=100000, L1: H=4,C=32 (HC=128), L2: H=1,C=32.
//
// R1: CSR gather instead of float-atomic scatter (1588 -> 826 us).
// R2: cooperative softmax via shfl broadcast (826 -> 734).
// R3: single-pass softmax, float4 loads, 8-deep unroll (734 -> 595).
// R4: atomic-free scatter; bf16 h payload; 16-deep unroll (595 -> 491).
// R5: both GEMMs -> bf16 MFMA 16x16x32, zero LDS/barriers (491 -> 443).
// R6: FAILED launch_bounds(256,8) -> allocator forced below need -> scratch
//     spills (WRITE 25->336 MB, gather1 128->236us). Reverted.
// R7: gather1 = R4-exact body (fp32 o1 out, VGPR 64 natural -> 8 waves);
//     gemm2 casts o1 fp32->bf16 in-register. Plain bounds everywhere.
// Self-loops are implicit: edge ids >= E map to (n,n).

typedef __bf16 bf16x8 __attribute__((ext_vector_type(8)));
typedef float f32x4 __attribute__((ext_vector_type(4)));

__device__ __forceinline__ float lrelu(float v) { return v >= 0.f ? v : 0.2f * v; }

__device__ __forceinline__ unsigned f2bf(float f) {   // RTNE f32->bf16 (finite inputs)
    unsigned u = __float_as_uint(f);
    return (u + 0x7FFFu + ((u >> 16) & 1u)) >> 16;
}

__device__ __forceinline__ bf16x8 as_bf16x8(uint4 u) {
    union { uint4 u; bf16x8 b; } c; c.u = u; return c.b;
}

__device__ __forceinline__ void bf16x8_fma(uint4 hv, float a, float* acc) {
    acc[0] = fmaf(a, __uint_as_float(hv.x << 16), acc[0]);
    acc[1] = fmaf(a, __uint_as_float(hv.x & 0xFFFF0000u), acc[1]);
    acc[2] = fmaf(a, __uint_as_float(hv.y << 16), acc[2]);
    acc[3] = fmaf(a, __uint_as_float(hv.y & 0xFFFF0000u), acc[3]);
    acc[4] = fmaf(a, __uint_as_float(hv.z << 16), acc[4]);
    acc[5] = fmaf(a, __uint_as_float(hv.z & 0xFFFF0000u), acc[5]);
    acc[6] = fmaf(a, __uint_as_float(hv.w << 16), acc[6]);
    acc[7] = fmaf(a, __uint_as_float(hv.w & 0xFFFF0000u), acc[7]);
}

// ---------------- weight cast: W1[128,128] -> w1t[c][k] bf16 ; W2 -> w2t[c][k]
__global__ __launch_bounds__(256) void cast_w_k(const float* __restrict__ W1,
                                                const float* __restrict__ W2,
                                                ushort* __restrict__ w1t,
                                                ushort* __restrict__ w2t) {
    int tid = blockIdx.x * 256 + threadIdx.x;
    if (tid < 16384) {
        int k = tid >> 7, c = tid & 127;
        w1t[c * 128 + k] = (ushort)f2bf(W1[tid]);
    }
    if (tid < 4096) {
        int k = tid >> 5, c = tid & 31;
        w2t[c * 128 + k] = (ushort)f2bf(W2[tid]);
    }
}

// ---------------- GEMM1 (MFMA): x[N,128]fp32 (cast in-reg) @ W1 -> h[N,128]bf16 + as/ad
// Block: 64 rows, 4 waves x 16 rows. 8 col-tiles, K=128 in 4 steps. No LDS.
__global__ __launch_bounds__(256) void gemm1_mfma(
    const float* __restrict__ x, const ushort* __restrict__ w1t,
    const float* __restrict__ atts, const float* __restrict__ attd,
    ushort* __restrict__ h, float* __restrict__ as_, float* __restrict__ ad_, int N) {
    const int w = threadIdx.x >> 6;
    const int l = threadIdx.x & 63;
    const int c15 = l & 15;
    const int quad = l >> 4;
    const int n_base = blockIdx.x * 64 + w * 16;
    const int n = n_base + c15;

    bf16x8 a[4];
    if (n < N) {
        const float4* xr = (const float4*)(x + (size_t)n * 128);
#pragma unroll
        for (int ks = 0; ks < 4; ks++) {
            float4 p0 = xr[ks * 8 + quad * 2];
            float4 p1 = xr[ks * 8 + quad * 2 + 1];
            uint4 u;
            u.x = f2bf(p0.x) | (f2bf(p0.y) << 16);
            u.y = f2bf(p0.z) | (f2bf(p0.w) << 16);
            u.z = f2bf(p1.x) | (f2bf(p1.y) << 16);
            u.w = f2bf(p1.z) | (f2bf(p1.w) << 16);
            a[ks] = as_bf16x8(u);
        }
    } else {
        uint4 z = make_uint4(0, 0, 0, 0);
#pragma unroll
        for (int ks = 0; ks < 4; ks++) a[ks] = as_bf16x8(z);
    }

    f32x4 acc[8];
#pragma unroll
    for (int ct = 0; ct < 8; ct++) acc[ct] = (f32x4){0.f, 0.f, 0.f, 0.f};

#pragma unroll
    for (int ct = 0; ct < 8; ct++) {
        const uint4* wr = (const uint4*)(w1t + (size_t)(ct * 16 + c15) * 128);
#pragma unroll
        for (int ks = 0; ks < 4; ks++) {
            bf16x8 bfrag = as_bf16x8(wr[ks * 4 + quad]);
            acc[ct] = __builtin_amdgcn_mfma_f32_16x16x32_bf16(a[ks], bfrag, acc[ct], 0, 0, 0);
        }
    }

    // h stores: lane holds col=ct*16+c15, rows n_base+quad*4+reg
#pragma unroll
    for (int ct = 0; ct < 8; ct++) {
        int col = ct * 16 + c15;
#pragma unroll
        for (int reg = 0; reg < 4; reg++) {
            int n_out = n_base + quad * 4 + reg;
            if (n_out < N) h[(size_t)n_out * 128 + col] = (ushort)f2bf(acc[ct][reg]);
        }
    }
    // attention logits per head (cols of head hh live in tiles 2hh, 2hh+1)
#pragma unroll
    for (int hh = 0; hh < 4; hh++) {
        float sA = atts[hh * 32 + c15], sB = atts[hh * 32 + 16 + c15];
        float dA = attd[hh * 32 + c15], dB = attd[hh * 32 + 16 + c15];
#pragma unroll
        for (int reg = 0; reg < 4; reg++) {
            float ps = acc[2 * hh][reg] * sA + acc[2 * hh + 1][reg] * sB;
            float pd = acc[2 * hh][reg] * dA + acc[2 * hh + 1][reg] * dB;
            ps += __shfl_xor(ps, 1); pd += __shfl_xor(pd, 1);
            ps += __shfl_xor(ps, 2); pd += __shfl_xor(pd, 2);
            ps += __shfl_xor(ps, 4); pd += __shfl_xor(pd, 4);
            ps += __shfl_xor(ps, 8); pd += __shfl_xor(pd, 8);
            int n_out = n_base + quad * 4 + reg;
            if (c15 == 0 && n_out < N) { as_[n_out * 4 + hh] = ps; ad_[n_out * 4 + hh] = pd; }
        }
    }
}

// ---------------- GEMM2 (MFMA): o1[N,128]fp32 (cast in-reg) @ W2 -> h2[N,32]bf16 + as/ad
__global__ __launch_bounds__(256) void gemm2_mfma(
    const float* __restrict__ ob, const ushort* __restrict__ w2t,
    const float* __restrict__ atts, const float* __restrict__ attd,
    ushort* __restrict__ h, float* __restrict__ as_, float* __restrict__ ad_, int N) {
    const int w = threadIdx.x >> 6;
    const int l = threadIdx.x & 63;
    const int c15 = l & 15;
    const int quad = l >> 4;
    const int n_base = blockIdx.x * 64 + w * 16;
    const int n = n_base + c15;

    bf16x8 a[4];
    if (n < N) {
        const float4* xr = (const float4*)(ob + (size_t)n * 128);
#pragma unroll
        for (int ks = 0; ks < 4; ks++) {
            float4 p0 = xr[ks * 8 + quad * 2];
            float4 p1 = xr[ks * 8 + quad * 2 + 1];
            uint4 u;
            u.x = f2bf(p0.x) | (f2bf(p0.y) << 16);
            u.y = f2bf(p0.z) | (f2bf(p0.w) << 16);
            u.z = f2bf(p1.x) | (f2bf(p1.y) << 16);
            u.w = f2bf(p1.z) | (f2bf(p1.w) << 16);
            a[ks] = as_bf16x8(u);
        }
    } else {
        uint4 z = make_uint4(0, 0, 0, 0);
#pragma unroll
        for (int ks = 0; ks < 4; ks++) a[ks] = as_bf16x8(z);
    }

    f32x4 acc[2];
#pragma unroll
    for (int ct = 0; ct < 2; ct++) acc[ct] = (f32x4){0.f, 0.f, 0.f, 0.f};

#pragma unroll
    for (int ct = 0; ct < 2; ct++) {
        const uint4* wr = (const uint4*)(w2t + (size_t)(ct * 16 + c15) * 128);
#pragma unroll
        for (int ks = 0; ks < 4; ks++) {
            bf16x8 bfrag = as_bf16x8(wr[ks * 4 + quad]);
            acc[ct] = __builtin_amdgcn_mfma_f32_16x16x32_bf16(a[ks], bfrag, acc[ct], 0, 0, 0);
        }
    }

#pragma unroll
    for (int ct = 0; ct < 2; ct++) {
        int col = ct * 16 + c15;
#pragma unroll
        for (int reg = 0; reg < 4; reg++) {
            int n_out = n_base + quad * 4 + reg;
            if (n_out < N) h[(size_t)n_out * 32 + col] = (ushort)f2bf(acc[ct][reg]);
        }
    }
    float sA = atts[c15], sB = atts[16 + c15];
    float dA = attd[c15], dB = attd[16 + c15];
#pragma unroll
    for (int reg = 0; reg < 4; reg++) {
        float ps = acc[0][reg] * sA + acc[1][reg] * sB;
        float pd = acc[0][reg] * dA + acc[1][reg] * dB;
        ps += __shfl_xor(ps, 1); pd += __shfl_xor(pd, 1);
        ps += __shfl_xor(ps, 2); pd += __shfl_xor(pd, 2);
        ps += __shfl_xor(ps, 4); pd += __shfl_xor(pd, 4);
        ps += __shfl_xor(ps, 8); pd += __shfl_xor(pd, 8);
        int n_out = n_base + quad * 4 + reg;
        if (c15 == 0 && n_out < N) { as_[n_out] = ps; ad_[n_out] = pd; }
    }
}

// ---------------- CSR build: hist+rank -> scan -> atomic-free scatter -------
__global__ __launch_bounds__(256) void hist_rank_k(const int* __restrict__ ei, int E, int N,
                                                   int* __restrict__ deg, int* __restrict__ rank) {
    int e = blockIdx.x * 256 + threadIdx.x;
    if (e >= E + N) return;
    int d = (e < E) ? ei[E + e] : e - E;
    rank[e] = atomicAdd(&deg[d], 1);
}

__global__ __launch_bounds__(256) void scan1_k(const int* __restrict__ deg,
                                               int* __restrict__ tmp, int* __restrict__ partial, int N) {
    __shared__ int sh[256];
    int i = blockIdx.x * 256 + threadIdx.x;
    int v = (i < N) ? deg[i] : 0;
    sh[threadIdx.x] = v;
    __syncthreads();
#pragma unroll
    for (int off = 1; off < 256; off <<= 1) {
        int t = (threadIdx.x >= off) ? sh[threadIdx.x - off] : 0;
        __syncthreads();
        sh[threadIdx.x] += t;
        __syncthreads();
    }
    if (i < N) tmp[i] = sh[threadIdx.x];
    if (threadIdx.x == 255) partial[blockIdx.x] = sh[255];
}

__global__ __launch_bounds__(1024) void scan2_k(int* __restrict__ partial, int B) {
    __shared__ int sh[1024];
    int i = threadIdx.x;
    int v = (i < B) ? partial[i] : 0;
    sh[i] = v;
    __syncthreads();
#pragma unroll
    for (int off = 1; off < 1024; off <<= 1) {
        int t = (i >= off) ? sh[i - off] : 0;
        __syncthreads();
        sh[i] += t;
        __syncthreads();
    }
    if (i < B) partial[i] = sh[i] - v;   // exclusive
}

__global__ __launch_bounds__(256) void scan3_k(const int* __restrict__ tmp, const int* __restrict__ partial,
                                               int* __restrict__ rs, int N) {
    int i = blockIdx.x * 256 + threadIdx.x;
    if (i < N) rs[i + 1] = tmp[i] + partial[blockIdx.x];
    if (i == 0) rs[0] = 0;
}

__global__ __launch_bounds__(256) void scatter_k(const int* __restrict__ ei, const int* __restrict__ rank,
                                                 const int* __restrict__ rs, int E, int N,
                                                 int* __restrict__ csr) {
    int e = blockIdx.x * 256 + threadIdx.x;
    if (e >= E + N) return;
    int s, d;
    if (e < E) { s = ei[e]; d = ei[E + e]; } else { s = e - E; d = s; }
    csr[rs[d] + rank[e]] = s;      // fire-and-forget random store
}

// ---------------- layer-1 gather: 16 lanes/dst, 8 bf16 ch/lane (uint4 loads),
// 16-edge chunks fully unrolled. R4-exact body: fp32 float4 output, natural
// VGPR 64 -> 8 waves/SIMD. (Bf16 pack epilogue costs +4 VGPR -> 7 waves; a
// forced (256,8) bound causes scratch spills. Measured R4/R5/R6.)
__global__ __launch_bounds__(256) void gather1_k(
    const int* __restrict__ rs, const int* __restrict__ csr,
    const float* __restrict__ as_, const float* __restrict__ ad_,
    const uint4* __restrict__ h, const float* __restrict__ b,
    float* __restrict__ o, int N) {
    const int jj = threadIdx.x & 31;
    const int l16 = jj & 15;
    const int sub = jj & 16;             // 16-lane subgroup base in 32-window
    const int d = blockIdx.x * 16 + (threadIdx.x >> 5) * 2 + (jj >> 4);
    if (d >= N) return;
    const int hl = l16 >> 2;             // my head
    const int sl = l16 & 3;              // my slot base
    const int beg = rs[d], end = rs[d + 1];
    const float adv = ad_[d * 4 + hl];

    float acc[8];
#pragma unroll
    for (int i = 0; i < 8; i++) acc[i] = 0.f;
    float den = 0.f;

    int j0 = beg;
    for (; j0 + 16 <= end; j0 += 16) {
        int sv0 = csr[j0 + sl];
        int sv1 = csr[j0 + sl + 4];
        int sv2 = csr[j0 + sl + 8];
        int sv3 = csr[j0 + sl + 12];
        float ex0 = __expf(fminf(lrelu(as_[sv0 * 4 + hl] + adv), 80.f));
        float ex1 = __expf(fminf(lrelu(as_[sv1 * 4 + hl] + adv), 80.f));
        float ex2 = __expf(fminf(lrelu(as_[sv2 * 4 + hl] + adv), 80.f));
        float ex3 = __expf(fminf(lrelu(as_[sv3 * 4 + hl] + adv), 80.f));
        den += ex0 + ex1 + ex2 + ex3;
#pragma unroll
        for (int k = 0; k < 4; k++) {
            float exk = (k == 0) ? ex0 : (k == 1) ? ex1 : (k == 2) ? ex2 : ex3;
            int   svk = (k == 0) ? sv0 : (k == 1) ? sv1 : (k == 2) ? sv2 : sv3;
#pragma unroll
            for (int q = 0; q < 4; q++) {
                int src = sub + (l16 & 12) + q;
                float a = __shfl(exk, src, 32);
                int   s = __shfl(svk, src, 32);
                uint4 hv = h[(size_t)s * 16 + l16];
                bf16x8_fma(hv, a, acc);
            }
        }
    }
    int r = end - j0;
    if (r > 0) {
        float exs[4] = {0.f, 0.f, 0.f, 0.f};
        int   svs[4] = {0, 0, 0, 0};
#pragma unroll
        for (int k = 0; k < 4; k++) {
            int slot = sl + 4 * k;
            if (slot < r) {
                int s = csr[j0 + slot];
                svs[k] = s;
                exs[k] = __expf(fminf(lrelu(as_[s * 4 + hl] + adv), 80.f));
                den += exs[k];
            }
        }
        for (int e = 0; e < r; e++) {
            int k = e >> 2, q = e & 3;
            float exk = (k == 0) ? exs[0] : (k == 1) ? exs[1] : (k == 2) ? exs[2] : exs[3];
            int   svk = (k == 0) ? svs[0] : (k == 1) ? svs[1] : (k == 2) ? svs[2] : svs[3];
            int src = sub + (l16 & 12) + q;
            float a = __shfl(exk, src, 32);
            int   s = __shfl(svk, src, 32);
            uint4 hv = h[(size_t)s * 16 + l16];
            bf16x8_fma(hv, a, acc);
        }
    }
    den += __shfl_xor(den, 1, 32);
    den += __shfl_xor(den, 2, 32);
    const float rcp = 1.f / (den + 1e-16f);
    float4 b0 = *(const float4*)&b[l16 * 8];
    float4 b1 = *(const float4*)&b[l16 * 8 + 4];
    float4 o0, o1v;
    o0.x  = fmaxf(acc[0] * rcp + b0.x, 0.f);
    o0.y  = fmaxf(acc[1] * rcp + b0.y, 0.f);
    o0.z  = fmaxf(acc[2] * rcp + b0.z, 0.f);
    o0.w  = fmaxf(acc[3] * rcp + b0.w, 0.f);
    o1v.x = fmaxf(acc[4] * rcp + b1.x, 0.f);
    o1v.y = fmaxf(acc[5] * rcp + b1.y, 0.f);
    o1v.z = fmaxf(acc[6] * rcp + b1.z, 0.f);
    o1v.w = fmaxf(acc[7] * rcp + b1.w, 0.f);
    *(float4*)&o[(size_t)d * 128 + l16 * 8]     = o0;
    *(float4*)&o[(size_t)d * 128 + l16 * 8 + 4] = o1v;
}

// ---------------- layer-2 gather: 4 lanes/dst, 8 bf16 ch/lane, 16-edge chunks.
__global__ __launch_bounds__(256) void gather2_k(
    const int* __restrict__ rs, const int* __restrict__ csr,
    const float* __restrict__ as_, const float* __restrict__ ad_,
    const uint4* __restrict__ h, const float* __restrict__ b,
    float* __restrict__ o, int N) {
    const int jj = threadIdx.x & 31;
    const int l4 = jj & 3;
    const int sub = jj & 28;             // 4-lane subgroup base
    const int d = blockIdx.x * 64 + (threadIdx.x >> 5) * 8 + (jj >> 2);
    if (d >= N) return;
    const int beg = rs[d], end = rs[d + 1];
    const float adv = ad_[d];

    float acc[8];
#pragma unroll
    for (int i = 0; i < 8; i++) acc[i] = 0.f;
    float den = 0.f;

    int j0 = beg;
    for (; j0 + 16 <= end; j0 += 16) {
        int sv0 = csr[j0 + l4];
        int sv1 = csr[j0 + l4 + 4];
        int sv2 = csr[j0 + l4 + 8];
        int sv3 = csr[j0 + l4 + 12];
        float ex0 = __expf(fminf(lrelu(as_[sv0] + adv), 80.f));
        float ex1 = __expf(fminf(lrelu(as_[sv1] + adv), 80.f));
        float ex2 = __expf(fminf(lrelu(as_[sv2] + adv), 80.f));
        float ex3 = __expf(fminf(lrelu(as_[sv3] + adv), 80.f));
        den += ex0 + ex1 + ex2 + ex3;
#pragma unroll
        for (int k = 0; k < 4; k++) {
            float exk = (k == 0) ? ex0 : (k == 1) ? ex1 : (k == 2) ? ex2 : ex3;
            int   svk = (k == 0) ? sv0 : (k == 1) ? sv1 : (k == 2) ? sv2 : sv3;
#pragma unroll
            for (int q = 0; q < 4; q++) {
                int src = sub + q;
                float a = __shfl(exk, src, 32);
                int   s = __shfl(svk, src, 32);
                uint4 hv = h[(size_t)s * 4 + l4];
                bf16x8_fma(hv, a, acc);
            }
        }
    }
    int r = end - j0;
    if (r > 0) {
        float exs[4] = {0.f, 0.f, 0.f, 0.f};
        int   svs[4] = {0, 0, 0, 0};
#pragma unroll
        for (int k = 0; k < 4; k++) {
            int slot = l4 + 4 * k;
            if (slot < r) {
                int s = csr[j0 + slot];
                svs[k] = s;
                exs[k] = __expf(fminf(lrelu(as_[s] + adv), 80.f));
                den += exs[k];
            }
        }
        for (int e = 0; e < r; e++) {
            int k = e >> 2, q = e & 3;
            float exk = (k == 0) ? exs[0] : (k == 1) ? exs[1] : (k == 2) ? exs[2] : exs[3];
            int   svk = (k == 0) ? svs[0] : (k == 1) ? svs[1] : (k == 2) ? svs[2] : svs[3];
            int src = sub + q;
            float a = __shfl(exk, src, 32);
            int   s = __shfl(svk, src, 32);
            uint4 hv = h[(size_t)s * 4 + l4];
            bf16x8_fma(hv, a, acc);
        }
    }
    den += __shfl_xor(den, 1, 32);
    den += __shfl_xor(den, 2, 32);
    const float rcp = 1.f / (den + 1e-16f);
    float4 b0 = *(const float4*)&b[l4 * 8];
    float4 b1 = *(const float4*)&b[l4 * 8 + 4];
    float4 o0, o1v;
    o0.x  = acc[0] * rcp + b0.x;
    o0.y  = acc[1] * rcp + b0.y;
    o0.z  = acc[2] * rcp + b0.z;
    o0.w  = acc[3] * rcp + b0.w;
    o1v.x = acc[4] * rcp + b1.x;
    o1v.y = acc[5] * rcp + b1.y;
    o1v.z = acc[6] * rcp + b1.z;
    o1v.w = acc[7] * rcp + b1.w;
    *(float4*)&o[(size_t)d * 32 + l4 * 8]     = o0;
    *(float4*)&o[(size_t)d * 32 + l4 * 8 + 4] = o1v;
}

extern "C" void kernel_launch(void* const* d_in, const int* in_sizes, int n_in,
                              void* d_out, int out_size, void* d_ws, size_t ws_size,
                              hipStream_t stream) {
    const float* x    = (const float*)d_in[0];
    const int*   ei   = (const int*)d_in[1];
    const float* W1   = (const float*)d_in[2];
    const float* as1v = (const float*)d_in[3];
    const float* ad1v = (const float*)d_in[4];
    const float* b1   = (const float*)d_in[5];
    const float* W2   = (const float*)d_in[6];
    const float* as2v = (const float*)d_in[7];
    const float* ad2v = (const float*)d_in[8];
    const float* b2   = (const float*)d_in[9];
    float* out = (float*)d_out;

    const int N = in_sizes[0] / 128;
    const int E = in_sizes[1] / 2;
    const int EN = E + N;
    const int B = (N + 255) / 256;   // scan chunks (must be <= 1024)

    // workspace layout
    char* base = (char*)d_ws;
    size_t o = 0;
    auto alloc = [&](size_t bytes) { void* p = base + o; o += (bytes + 255) & ~(size_t)255; return p; };
    ushort* w1t  = (ushort*)alloc((size_t)128 * 128 * 2);
    ushort* w2t  = (ushort*)alloc((size_t)32 * 128 * 2);
    ushort* h1   = (ushort*)alloc((size_t)N * 128 * 2);
    ushort* h2   = (ushort*)alloc((size_t)N * 32 * 2);
    float*  o1   = (float*)alloc((size_t)N * 128 * 4);
    float*  as1  = (float*)alloc((size_t)N * 4 * 4);
    float*  ad1  = (float*)alloc((size_t)N * 4 * 4);
    float*  as2  = (float*)alloc((size_t)N * 4);
    float*  ad2  = (float*)alloc((size_t)N * 4);
    int*    deg  = (int*)alloc((size_t)N * 4);
    int*    tmp  = (int*)alloc((size_t)N * 4);
    int*    part = (int*)alloc((size_t)1024 * 4);
    int*    rs   = (int*)alloc((size_t)(N + 1) * 4);
    int*    rank = (int*)alloc((size_t)EN * 4);
    int*    csr  = (int*)alloc((size_t)EN * 4);

    hipMemsetAsync(deg, 0, (size_t)N * 4, stream);

    const int nbE = (EN + 255) / 256;
    const int nbN = (N + 255) / 256;
    const int nbG = (N + 63) / 64;

    // ---- weight cast + layer-1 GEMM (MFMA, fused x cast) + CSR build
    cast_w_k<<<64, 256, 0, stream>>>(W1, W2, w1t, w2t);
    gemm1_mfma<<<nbG, 256, 0, stream>>>(x, w1t, as1v, ad1v, h1, as1, ad1, N);
    hist_rank_k<<<nbE, 256, 0, stream>>>(ei, E, N, deg, rank);
    scan1_k<<<nbN, 256, 0, stream>>>(deg, tmp, part, N);
    scan2_k<<<1, 1024, 0, stream>>>(part, B);
    scan3_k<<<nbN, 256, 0, stream>>>(tmp, part, rs, N);
    scatter_k<<<nbE, 256, 0, stream>>>(ei, rank, rs, E, N, csr);

    // ---- layer 1 edge softmax + aggregate + bias + relu -> o1 (fp32)
    gather1_k<<<(N + 15) / 16, 256, 0, stream>>>(rs, csr, as1, ad1, (const uint4*)h1, b1, o1, N);

    // ---- layer 2
    gemm2_mfma<<<nbG, 256, 0, stream>>>(o1, w2t, as2v, ad2v, h2, as2, ad2, N);
    gather2_k<<<(N + 63) / 64, 256, 0, stream>>>(rs, csr, as2, ad2, (const uint4*)h2, b2, out, N);
}